// Round 9
// baseline (3418.477 us; speedup 1.0000x reference)
//
#include <hip/hip_runtime.h>

#define NTIME 30
#define NB 4096

typedef __attribute__((ext_vector_type(8))) short short8;
typedef __attribute__((ext_vector_type(8))) _Float16 half8;
typedef __attribute__((ext_vector_type(4))) float f32x4;
typedef __attribute__((ext_vector_type(16))) float f32x16;

__device__ __forceinline__ unsigned short f2h(float f) {
    _Float16 h = (_Float16)f;                  // RNE
    unsigned short u; __builtin_memcpy(&u, &h, 2); return u;
}
__device__ __forceinline__ float h2f(unsigned short u) {
    _Float16 h; __builtin_memcpy(&h, &u, 2); return (float)h;
}
__device__ __forceinline__ half8 s2h8(short8 s) {
    union { short8 s; half8 h; } u; u.s = s; return u.h;
}
__device__ __forceinline__ float sigf(float x)     { return 1.0f / (1.0f + __expf(-x)); }
__device__ __forceinline__ float tanhfast(float x) { return 1.0f - 2.0f / (__expf(2.0f * x) + 1.0f); }

// AGPR-resident carried state (see r6/r7 notes). Non-volatile: data deps
// preserve ordering, scheduler keeps placement freedom.
__device__ __forceinline__ float ag_in(float v) {
    float r;
    asm("v_accvgpr_write_b32 %0, %1" : "=a"(r) : "v"(v));
    return r;
}
__device__ __forceinline__ float ag_out(float a) {
    float r;
    asm("v_accvgpr_read_b32 %0, %1" : "=v"(r) : "a"(a));
    return r;
}

// LDS-only barrier: all cross-wave communication inside lstm3 is via LDS, so we
// only need lgkmcnt(0)+s_barrier. Does NOT drain vmcnt -> global weight
// prefetches stay in flight across phase boundaries.
__device__ __forceinline__ void bar_lds() {
    asm volatile("s_waitcnt lgkmcnt(0)" ::: "memory");
    __builtin_amdgcn_s_barrier();
    asm volatile("" ::: "memory");
}

// ---- L1 weight pack: 32x32x16 B-frags, SINGLE fp16 plane.
__global__ __launch_bounds__(256) void prep_w32s(const float* __restrict__ Wih,
                                                 const float* __restrict__ Whh,
                                                 unsigned short* __restrict__ out)
{
    int e = blockIdx.x * 256 + threadIdx.x;
    if (e >= 36 * 32768) return;
    int j    = e & 7;
    int lane = (e >> 3) & 63;
    int g    = (e >> 9) & 3;
    int w    = (e >> 11) & 15;
    int s    = e >> 15;
    int n = lane & 31, kh = lane >> 5;
    int unit = w * 32 + n;
    int k = s * 16 + kh * 8 + j;
    int row = g * 512 + unit;
    float v = 0.0f;
    if (k < 64) { if (k < 58) v = Wih[row * 58 + k]; }
    else        { v = Whh[row * 512 + (k - 64)]; }
    out[e] = f2h(v);
}

// ---- L2/L3 weight pack: 16x16x32 B-frags, single fp16 plane.
__global__ __launch_bounds__(256) void prep_w16s(const float* __restrict__ Wih,
                                                 const float* __restrict__ Whh,
                                                 unsigned short* __restrict__ out,
                                                 int H, int KI, int KIp, int KH, int CG, int KS)
{
    int e = blockIdx.x * 256 + threadIdx.x;
    if (e >= KS * CG * 2048) return;
    int j    = e & 7;
    int lane = (e >> 3) & 63;
    int g    = (e >> 9) & 3;
    int rest = e >> 11;
    int cg = rest % CG;
    int s  = rest / CG;
    int n = lane & 15, q = lane >> 4;
    int unit = cg * 16 + n;
    int k = s * 32 + q * 8 + j;
    int row = g * H + unit;
    float v = 0.0f;
    if (k < KIp) { if (k < KI) v = Wih[row * KI + k]; }
    else         { v = Whh[row * KH + (k - KIp)]; }
    out[e] = f2h(v);
}

// ---- x pre-pack: x[B,F,T] -> fp16 xT2[wg][t][32 rows][64 f] (per-WG LDS layout).
__global__ __launch_bounds__(256) void prep_xt2(const float* __restrict__ x1,
                                                const float* __restrict__ x2,
                                                unsigned short* __restrict__ xT)
{
    __shared__ float tile[1740];
    int blk = blockIdx.x;               // [0, 8192): br*4096 + s
    int br = blk >> 12;
    int s  = blk & 4095;
    const float* xp = (br ? x2 : x1) + (size_t)s * 1740;
    for (int i = threadIdx.x; i < 1740; i += 256) tile[i] = xp[i];
    __syncthreads();
    int wg = s >> 4, row = (br << 4) | (s & 15);
    unsigned short* dst = xT + ((size_t)wg * 30 * 32 + row) * 64;
    for (int i = threadIdx.x; i < 1920; i += 256) {
        int t = i >> 6, f = i & 63;
        dst[(size_t)t * 2048 + f] = f2h((f < 58) ? tile[f * 30 + t] : 0.0f);
    }
}

// ---- Head weight transposes (o-fastest float4 blocks)
__global__ __launch_bounds__(256) void pack_wt1(const float* __restrict__ Wf1, float4* __restrict__ WT1)
{
    int e = blockIdx.x * 256 + threadIdx.x;
    if (e >= 480 * 1024) return;
    int kc = e >> 10, o = e & 1023;
    float4 v = {0.0f, 0.0f, 0.0f, 0.0f};
    if (o < 960) {
        const float* p = Wf1 + (size_t)o * 1920 + kc * 4;
        v.x = p[0]; v.y = p[1]; v.z = p[2]; v.w = p[3];
    }
    WT1[e] = v;
}
__global__ __launch_bounds__(256) void pack_wt2(const float* __restrict__ Wf2, float4* __restrict__ WT2)
{
    int e = blockIdx.x * 256 + threadIdx.x;
    if (e >= 256 * 512) return;
    int kc = e >> 9, o = e & 511;
    float4 v = {0.0f, 0.0f, 0.0f, 0.0f};
    if (o < 480) {
        int k = kc * 4;
        v.x = (k + 0 < 960) ? Wf2[(size_t)o * 960 + k + 0] : 0.0f;
        v.y = (k + 1 < 960) ? Wf2[(size_t)o * 960 + k + 1] : 0.0f;
        v.z = (k + 2 < 960) ? Wf2[(size_t)o * 960 + k + 2] : 0.0f;
        v.w = (k + 3 < 960) ? Wf2[(size_t)o * 960 + k + 3] : 0.0f;
    }
    WT2[e] = v;
}

#define MFMA32(A, X, B) A = __builtin_amdgcn_mfma_f32_32x32x16_f16((X), (B), (A), 0, 0, 0)
#define MFMA16(A, X, B) A = __builtin_amdgcn_mfma_f32_16x16x32_f16((X), (B), (A), 0, 0, 0)

// L1 A-fragment load (x for s<4, h1(t-1) in read buffer h1r otherwise).
#define L1_LOAD_A(SV) do { \
    if ((SV) < 4) { \
        a = *(const half8*)(xh + n1 * 72 + (SV) * 16 + kh * 8); \
    } else { \
        a = *(const half8*)(h1r + n1 * 520 + ((SV) - 4) * 16 + kh * 8); \
    } } while (0)

// one L1 k-step of a 2-gate pass (gate byte-offsets GA, GB within a slab):
// 2 MFMAs, depth-3 rotating refill.
#define L1_SUB(WA, WB, IDX, GA, GB) do { \
    const int _s = rev ? (35 - (ss + (IDX))) : (ss + (IDX)); \
    half8 a; \
    L1_LOAD_A(_s); \
    if (ss + (IDX) + 3 < 36) { \
        const int _sn = rev ? (35 - (ss + (IDX) + 3)) : (ss + (IDX) + 3); \
        const unsigned short* _bb = B1p + _sn * 32768; \
        MFMA32(P0, a, WA); \
        MFMA32(P1, a, WB); \
        WA = *(const half8*)(_bb + (GA)); \
        WB = *(const half8*)(_bb + (GB)); \
    } else { \
        MFMA32(P0, a, WA); \
        MFMA32(P1, a, WB); \
    } } while (0)

#define L1_KLOOP(GA, GB) \
    _Pragma("unroll 1") \
    for (int ss = 0; ss < 36; ss += 3) { \
        L1_SUB(w0a, w0b, 0, GA, GB); \
        L1_SUB(w1a, w1b, 1, GA, GB); \
        L1_SUB(w2a, w2b, 2, GA, GB); \
    }

// entry prefetch of the first 3 k-steps of a pass. RV = direction of that pass.
#define L1_ENTRY(GA, GB, RV) do { \
    const int _s0 = (RV) ? 35 : 0, _s1 = (RV) ? 34 : 1, _s2 = (RV) ? 33 : 2; \
    const unsigned short* _b0 = B1p + _s0 * 32768; \
    const unsigned short* _b1 = B1p + _s1 * 32768; \
    const unsigned short* _b2 = B1p + _s2 * 32768; \
    w0a = *(const half8*)(_b0 + (GA)); w0b = *(const half8*)(_b0 + (GB)); \
    w1a = *(const half8*)(_b1 + (GA)); w1b = *(const half8*)(_b1 + (GB)); \
    w2a = *(const half8*)(_b2 + (GA)); w2b = *(const half8*)(_b2 + (GB)); \
} while (0)

#define L2_LOAD_A(SV) do { \
    if ((SV) < 16) { \
        short8 _a = *(const short8*)(h1w + row2 * 520 + (SV) * 32 + quad * 8); \
        short8 _msk = _a >> 15; \
        a = s2h8(_a & ~_msk); \
    } else { \
        a = *(const half8*)(h2b + cur * 4352 + row2 * 136 + ((SV) - 16) * 32 + quad * 8); \
    } } while (0)

// one L2 k-step, all 4 gates: 4 MFMAs, depth-2 ping-pong refill.
#define L2_SUB(Q0, Q1, Q2, Q3, IDX) do { \
    const int _s = rev ? (19 - (ss + (IDX))) : (ss + (IDX)); \
    half8 a; \
    L2_LOAD_A(_s); \
    MFMA16(A0, a, Q0); \
    MFMA16(A1, a, Q1); \
    MFMA16(A2, a, Q2); \
    MFMA16(A3, a, Q3); \
    if (ss + (IDX) + 2 < 20) { \
        const int _sn = rev ? (19 - (ss + (IDX) + 2)) : (ss + (IDX) + 2); \
        const unsigned short* _bb = B2p + _sn * 16384; \
        Q0 = *(const half8*)(_bb); \
        Q1 = *(const half8*)(_bb + 512); \
        Q2 = *(const half8*)(_bb + 1024); \
        Q3 = *(const half8*)(_bb + 1536); \
    } } while (0)

#define L2_ENTRY() do { \
    const int _s0 = rev ? 19 : 0, _s1 = rev ? 18 : 1; \
    const unsigned short* _b0 = B2p + _s0 * 16384; \
    const unsigned short* _b1 = B2p + _s1 * 16384; \
    qa0 = *(const half8*)(_b0);        qa1 = *(const half8*)(_b0 + 512); \
    qa2 = *(const half8*)(_b0 + 1024); qa3 = *(const half8*)(_b0 + 1536); \
    qb0 = *(const half8*)(_b1);        qb1 = *(const half8*)(_b1 + 512); \
    qb2 = *(const half8*)(_b1 + 1024); qb3 = *(const half8*)(_b1 + 1536); \
} while (0)

#define L3_LOAD_A(SV) do { \
    if ((SV) < 4) { \
        short8 _a = *(const short8*)(h2b + nxt * 4352 + row3 * 136 + (SV) * 32 + quad * 8); \
        short8 _msk = _a >> 15; \
        a = s2h8(_a & ~_msk); \
    } else { \
        a = *(const half8*)(h3b + cur * 2304 + row3 * 72 + ((SV) - 4) * 32 + quad * 8); \
    } } while (0)

#define L3_SUB(Q0, Q1, Q2, Q3, IDX) do { \
    const int _s = rev ? (5 - (ss + (IDX))) : (ss + (IDX)); \
    half8 a; \
    L3_LOAD_A(_s); \
    MFMA16(A0, a, Q0); \
    MFMA16(A1, a, Q1); \
    MFMA16(A2, a, Q2); \
    MFMA16(A3, a, Q3); \
    if (ss + (IDX) + 2 < 6) { \
        const int _sn = rev ? (5 - (ss + (IDX) + 2)) : (ss + (IDX) + 2); \
        const unsigned short* _bb = B3p + _sn * 8192; \
        Q0 = *(const half8*)(_bb); \
        Q1 = *(const half8*)(_bb + 512); \
        Q2 = *(const half8*)(_bb + 1024); \
        Q3 = *(const half8*)(_bb + 1536); \
    } } while (0)

#define L3_ENTRY_A() do { \
    const int _s0 = rev ? 5 : 0; \
    const unsigned short* _b0 = B3p + _s0 * 8192; \
    ra0 = *(const half8*)(_b0);        ra1 = *(const half8*)(_b0 + 512); \
    ra2 = *(const half8*)(_b0 + 1024); ra3 = *(const half8*)(_b0 + 1536); \
} while (0)

#define L3_ENTRY_B() do { \
    const int _s1 = rev ? 4 : 1; \
    const unsigned short* _b1 = B3p + _s1 * 8192; \
    rb0 = *(const half8*)(_b1);        rb1 = *(const half8*)(_b1 + 512); \
    rb2 = *(const half8*)(_b1 + 1024); rb3 = *(const half8*)(_b1 + 1536); \
} while (0)

// ---- Fused Siamese 3-layer LSTM. 256 WGs x 1024 thr (16 waves, 4/SIMD), 100KB LDS.
// Round-18 (v11): v10 with the xtmode staging bug fixed — round 8 staged only
// rows 0-15 (x1 branch) in the hot loop, leaving x2 frozen at x2(0) (absmax
// 8.3e-3). Now both rows (b and 16+b) are loaded and written, mirroring the
// non-xt path. All v10 mechanisms retained: h1 double-buffer (barrier B
// deleted, 3 barriers/t), fp16 pre-packed x, non-volatile AGPR moves.
__global__ __launch_bounds__(1024, 4) void lstm3_v11(
    const float* __restrict__ x1, const float* __restrict__ x2,
    const unsigned short* __restrict__ xt2, const int xtmode,
    const unsigned short* __restrict__ l1w, const unsigned short* __restrict__ l2w,
    const unsigned short* __restrict__ l3w,
    const float* __restrict__ b1, const float* __restrict__ b2, const float* __restrict__ b3,
    float* __restrict__ dbuf)
{
    extern __shared__ unsigned short sm[];
    unsigned short* h1b = sm;                    // [2][32][520]
    unsigned short* h2b = h1b + 2 * 32 * 520;    // [2][32][136]
    unsigned short* h3b = h2b + 2 * 32 * 136;    // [2][32][72]
    unsigned short* xb  = h3b + 2 * 32 * 72;     // [2][32][72] double-buffered
    // total 51200 shorts = 102400 B

    const int tid  = threadIdx.x;
    const int wv   = tid >> 6;
    const int lane = tid & 63;
    const int wg   = blockIdx.x;
    const int samp0 = wg * 16;

    {
        unsigned int* p = (unsigned int*)sm;
        for (int i = tid; i < 25600; i += 1024) p[i] = 0u;
    }

    // L1 lane mapping (32x32)
    const int n1 = lane & 31;
    const int kh = lane >> 5;
    const int u1 = wv * 32 + n1;
    // L2/L3 lane mapping (16x16)
    const int n2   = lane & 15;
    const int quad = lane >> 4;
    const int mt2  = wv >> 3, cg2 = wv & 7;
    const int u2   = cg2 * 16 + n2;
    const int row2 = mt2 * 16 + n2;
    const int mt3  = (wv >> 2) & 1, cg3 = wv & 3;
    const int u3   = cg3 * 16 + n2;
    const int row3 = mt3 * 16 + n2;

    // carried state, AGPR-resident
    float c1a[16], iga[16], c2a[4], c3a[4];
    #pragma unroll
    for (int r = 0; r < 16; ++r) { c1a[r] = ag_in(0.0f); iga[r] = ag_in(0.0f); }
    #pragma unroll
    for (int r = 0; r < 4; ++r) { c2a[r] = ag_in(0.0f); c3a[r] = ag_in(0.0f); }

    const unsigned short* B1p = l1w + wv * 2048 + lane * 8;
    const unsigned short* B2p = l2w + cg2 * 2048 + lane * 8;
    const unsigned short* B3p = l3w + cg3 * 2048 + lane * 8;

    // register pools
    half8 w0a, w0b, w1a, w1b, w2a, w2b;             // L1 rotation (24 VGPR)
    half8 qa0, qa1, qa2, qa3, qb0, qb1, qb2, qb3;   // L2 ping-pong (32 VGPR)
    half8 ra0, ra1, ra2, ra3, rb0, rb1, rb2, rb3;   // L3 ping-pong (32 VGPR)

    // t=0 pass0 entry prefetch (fwd direction, gates i,g at offsets 0,1024)
    L1_ENTRY(0, 1024, false);

    // stage x_0 into parity-0 buffer (prologue; covers all 32 rows)
    for (int e = tid; e < 2048; e += 1024) {
        int b = e >> 6, f = e & 63;
        if (xtmode) {
            xb[b * 72 + f] = xt2[(((size_t)wg * 30 + 0) * 32 + b) * 64 + f];
        } else {
            const float* __restrict__ xp = (b < 16) ? x1 : x2;
            float v = (f < 58) ? xp[(samp0 + (b & 15)) * 1740 + f * 30 + 0] : 0.0f;
            xb[b * 72 + f] = f2h(v);
        }
    }
    bar_lds();

    int cur = 0, cur1 = 0;
    #pragma unroll 1
    for (int t = 0; t < NTIME; ++t) {
        const bool rev = (t & 1);
        const int nxt = cur ^ 1;
        const int nxt1 = cur1 ^ 1;
        const unsigned short* xh = xb + (t & 1) * 2304;
        const unsigned short* h1r = h1b + cur1 * 16640;   // h1(t-1), read-only
        unsigned short* h1w = h1b + nxt1 * 16640;         // h1(t), written this step

        // ===== L1 pass 0: gates i,g -> ig = sig(i)*tanh(g), AGPR-resident =====
        {
            f32x16 P0, P1;
            #pragma unroll
            for (int r = 0; r < 16; ++r) { P0[r] = 0.0f; P1[r] = 0.0f; }
            float bgi = b1[u1], bgg = b1[1024 + u1];
            L1_KLOOP(0, 1024);
            L1_ENTRY(512, 1536, rev);     // pass1 entry (gates f,o), hides under epilogue
            #pragma unroll
            for (int r = 0; r < 16; ++r) {
                iga[r] = ag_in(sigf(P0[r] + bgi) * tanhfast(P1[r] + bgg));
            }
        }
        // ===== L1 pass 1: gates f,o -> cell update + h; writes go to h1w (no
        // barrier needed: reads target h1r, a different buffer) =====
        {
            f32x16 P0, P1;
            #pragma unroll
            for (int r = 0; r < 16; ++r) { P0[r] = 0.0f; P1[r] = 0.0f; }
            float bgf = b1[512 + u1], bgo = b1[1536 + u1];
            L1_KLOOP(512, 1536);
            #pragma unroll
            for (int r = 0; r < 16; ++r) {
                float F = sigf(P0[r] + bgf);
                float O = sigf(P1[r] + bgo);
                float c = F * ag_out(c1a[r]) + ag_out(iga[r]);
                c1a[r] = ag_in(c);
                float h = O * tanhfast(c);
                int row = (r & 3) + 8 * (r >> 2) + 4 * kh;   // verified 32x32 C-map
                h1w[row * 520 + u1] = f2h(h);
            }
        }
        bar_lds();   // C: h1(t) visible

        // x(t+1): issue the coalesced global loads (both branches) first, then L2
        // weight entry, LDS writes last.
        unsigned short xv16a = 0, xv16b = 0;
        float xv0 = 0.0f, xv1 = 0.0f;
        if (t + 1 < NTIME) {
            int b = tid >> 6, f = tid & 63;
            if (xtmode) {
                const unsigned short* p = xt2 + (((size_t)wg * 30 + (t + 1)) * 32 + b) * 64 + f;
                xv16a = p[0];
                xv16b = p[16 * 64];    // x2 branch rows (16..31)
            } else {
                int idx = (samp0 + b) * 1740 + f * 30 + (t + 1);
                xv0 = (f < 58) ? x1[idx] : 0.0f;
                xv1 = (f < 58) ? x2[idx] : 0.0f;
            }
        }

        L2_ENTRY();   // L2 entry frags (overlaps x write)

        if (t + 1 < NTIME) {
            unsigned short* xb2 = xb + ((t + 1) & 1) * 2304;
            int b = tid >> 6, f = tid & 63;
            if (xtmode) {
                xb2[b * 72 + f] = xv16a;
                xb2[(16 + b) * 72 + f] = xv16b;
            } else {
                xb2[b * 72 + f] = f2h(xv0);
                xb2[(16 + b) * 72 + f] = f2h(xv1);
            }
        }

        // ===== L2: single 4-gate pass; k = [relu(h1) 512 | h2 128], 20 ksteps =====
        {
            f32x4 A0 = {0.0f, 0.0f, 0.0f, 0.0f};
            f32x4 A1 = {0.0f, 0.0f, 0.0f, 0.0f};
            f32x4 A2 = {0.0f, 0.0f, 0.0f, 0.0f};
            f32x4 A3 = {0.0f, 0.0f, 0.0f, 0.0f};
            float bg0 = b2[u2], bg1 = b2[128 + u2], bg2 = b2[256 + u2], bg3 = b2[384 + u2];
            #pragma unroll 1
            for (int ss = 0; ss < 20; ss += 2) {
                L2_SUB(qa0, qa1, qa2, qa3, 0);
                L2_SUB(qb0, qb1, qb2, qb3, 1);
            }
            if (wv < 8) { L3_ENTRY_A(); }   // only set A (16 regs) across bar D
            #pragma unroll
            for (int r = 0; r < 4; ++r) {
                float I = sigf(A0[r] + bg0);
                float F = sigf(A1[r] + bg1);
                float G = tanhfast(A2[r] + bg2);
                float O = sigf(A3[r] + bg3);
                float c = F * ag_out(c2a[r]) + I * G;
                c2a[r] = ag_in(c);
                float h = O * tanhfast(c);
                int row = mt2 * 16 + quad * 4 + r;
                h2b[nxt * 4352 + row * 136 + u2] = f2h(h);
            }
        }
        bar_lds();   // D: h2(t) + x(t+1) visible

        // ===== L3: single 4-gate pass; k = [relu(h2) 128 | h3 64], 6 ksteps, waves 0-7 =====
        if (wv < 8) {
            f32x4 A0 = {0.0f, 0.0f, 0.0f, 0.0f};
            f32x4 A1 = {0.0f, 0.0f, 0.0f, 0.0f};
            f32x4 A2 = {0.0f, 0.0f, 0.0f, 0.0f};
            f32x4 A3 = {0.0f, 0.0f, 0.0f, 0.0f};
            float bg0 = b3[u3], bg1 = b3[64 + u3], bg2 = b3[128 + u3], bg3 = b3[192 + u3];
            L3_ENTRY_B();   // set B fetched post-barrier, covered by first L3_SUB
            #pragma unroll 1
            for (int ss = 0; ss < 6; ss += 2) {
                L3_SUB(ra0, ra1, ra2, ra3, 0);
                L3_SUB(rb0, rb1, rb2, rb3, 1);
            }
            #pragma unroll
            for (int r = 0; r < 4; ++r) {
                float I = sigf(A0[r] + bg0);
                float F = sigf(A1[r] + bg1);
                float G = tanhfast(A2[r] + bg2);
                float O = sigf(A3[r] + bg3);
                float c = F * ag_out(c3a[r]) + I * G;
                c3a[r] = ag_in(c);
                float h = O * tanhfast(c);
                int row = mt3 * 16 + quad * 4 + r;
                h3b[nxt * 2304 + row * 72 + u3] = f2h(h);
            }
        }

        // next-t pass0 entry prefetch: issued before bar E + d-write, survives the
        // backedge (LDS-only barriers keep vmcnt).
        if (t + 1 < NTIME) {
            L1_ENTRY(0, 1024, !rev);
        }
        bar_lds();   // E: h3(t) visible

        // d = |relu(h3_x1) - relu(h3_x2)| -> global
        {
            int b = tid >> 6, u = tid & 63;
            float ha = h2f(h3b[nxt * 2304 + b * 72 + u]);
            float hb = h2f(h3b[nxt * 2304 + (16 + b) * 72 + u]);
            dbuf[(size_t)(samp0 + b) * 1920 + t * 64 + u] = fabsf(fmaxf(ha, 0.0f) - fmaxf(hb, 0.0f));
        }
        cur = nxt;
        cur1 = nxt1;
    }
}

// ---- FC head v2
__global__ __launch_bounds__(512) void head_v2(
    const float* __restrict__ dg,
    const float4* __restrict__ WT1, const float* __restrict__ bf1,
    const float4* __restrict__ WT2, const float* __restrict__ bf2,
    const float* __restrict__ Wf3, const float* __restrict__ bf3,
    const float* __restrict__ Wf4, const float* __restrict__ bf4,
    float* __restrict__ out)
{
    extern __shared__ float hds[];
    float* ds = hds;                  // [16][1928] during fc1
    float* a1 = hds;                  // [16][1032] overlay after fc1
    float* a2 = a1 + 16 * 1032;       // [16][520]
    float* a3 = a2 + 16 * 520;        // [16][16]

    const int tid = threadIdx.x;
    const int samp0 = blockIdx.x * 16;

    for (int e = tid; e < 16 * 480; e += 512) {
        int b = e / 480, jc = e - b * 480;
        const float* src = dg + (size_t)(samp0 + b) * 1920 + jc * 4;
        float* dst = ds + b * 1928 + jc * 4;
        dst[0] = src[0]; dst[1] = src[1]; dst[2] = src[2]; dst[3] = src[3];
    }
    __syncthreads();

    const int w = tid >> 6, lane = tid & 63;
    const int oA = w * 128 + lane, oB = oA + 64;
    float accA[16], accB[16];
    {
        float bA = (oA < 960) ? bf1[oA] : 0.0f;
        float bB = (oB < 960) ? bf1[oB] : 0.0f;
        #pragma unroll
        for (int r = 0; r < 16; ++r) { accA[r] = bA; accB[r] = bB; }
    }
    #pragma unroll 2
    for (int kc = 0; kc < 480; ++kc) {
        float4 wA = WT1[kc * 1024 + oA];
        float4 wB = WT1[kc * 1024 + oB];
        #pragma unroll
        for (int r = 0; r < 16; ++r) {
            float4 d4 = ((const float4*)(ds + r * 1928))[kc];
            accA[r] += d4.x * wA.x + d4.y * wA.y + d4.z * wA.z + d4.w * wA.w;
            accB[r] += d4.x * wB.x + d4.y * wB.y + d4.z * wB.z + d4.w * wB.w;
        }
    }
    __syncthreads();
    #pragma unroll
    for (int r = 0; r < 16; ++r) {
        a1[r * 1032 + oA] = fmaxf(accA[r], 0.0f);
        a1[r * 1032 + oB] = fmaxf(accB[r], 0.0f);
    }
    __syncthreads();

    const int o2 = tid;
    float acc2[16];
    {
        float b = (o2 < 480) ? bf2[o2] : 0.0f;
        #pragma unroll
        for (int r = 0; r < 16; ++r) acc2[r] = b;
    }
    #pragma unroll 2
    for (int kc = 0; kc < 256; ++kc) {
        float4 w4 = WT2[kc * 512 + o2];
        #pragma unroll
        for (int r = 0; r < 16; ++r) {
            float4 a4 = ((const float4*)(a1 + r * 1032))[kc];
            acc2[r] += a4.x * w4.x + a4.y * w4.y + a4.z * w4.z + a4.w * w4.w;
        }
    }
    #pragma unroll
    for (int r = 0; r < 16; ++r) a2[r * 520 + o2] = fmaxf(acc2[r], 0.0f);
    __syncthreads();

    if (tid < 256) {
        int o = tid & 15, r = tid >> 4;
        float acc = bf3[o];
        const float4* wr = (const float4*)(Wf3 + (size_t)o * 480);
        const float4* av = (const float4*)(a2 + r * 520);
        #pragma unroll 4
        for (int kc = 0; kc < 120; ++kc) {
            float4 a4 = av[kc];
            float4 w4 = wr[kc];
            acc += a4.x * w4.x + a4.y * w4.y + a4.z * w4.z + a4.w * w4.w;
        }
        a3[r * 16 + o] = fmaxf(acc, 0.0f);
    }
    __syncthreads();

    if (tid < 16) {
        float acc = bf4[0];
        #pragma unroll
        for (int k = 0; k < 16; ++k) acc += a3[tid * 16 + k] * Wf4[k];
        out[samp0 + tid] = acc;
    }
}

extern "C" void kernel_launch(void* const* d_in, const int* in_sizes, int n_in,
                              void* d_out, int out_size, void* d_ws, size_t ws_size,
                              hipStream_t stream) {
    const float* x1   = (const float*)d_in[0];
    const float* x2   = (const float*)d_in[1];
    const float* Wih1 = (const float*)d_in[2];
    const float* Whh1 = (const float*)d_in[3];
    const float* b1   = (const float*)d_in[4];
    const float* Wih2 = (const float*)d_in[5];
    const float* Whh2 = (const float*)d_in[6];
    const float* b2   = (const float*)d_in[7];
    const float* Wih3 = (const float*)d_in[8];
    const float* Whh3 = (const float*)d_in[9];
    const float* b3   = (const float*)d_in[10];
    const float* Wf1  = (const float*)d_in[11];
    const float* bf1  = (const float*)d_in[12];
    const float* Wf2  = (const float*)d_in[13];
    const float* bf2  = (const float*)d_in[14];
    const float* Wf3  = (const float*)d_in[15];
    const float* bf3  = (const float*)d_in[16];
    const float* Wf4  = (const float*)d_in[17];
    const float* bf4  = (const float*)d_in[18];

    float* wsf = (float*)d_ws;
    float* dbuf = wsf;                                         // 4096*1920 = 7,864,320 f32
    unsigned short* l1w = (unsigned short*)(wsf + 7864320);    // 36*32768 = 1,179,648 us
    unsigned short* l2w = l1w + 1179648;                       // 20*8*2048 =  327,680 us
    unsigned short* l3w = l2w + 327680;                        //  6*4*2048 =   49,152 us
    float4* WT1 = (float4*)(wsf + 8642560);                    // 480*1024 float4
    float4* WT2 = WT1 + 480 * 1024;                            // 256*512  float4
    unsigned short* xt2 = (unsigned short*)(wsf + 11132928);   // 256*30*32*64 = 15,728,640 us
    float* out = (float*)d_out;

    const size_t need_bytes = (size_t)11132928 * 4u + (size_t)15728640 * 2u;
    const int xtmode = (ws_size >= need_bytes) ? 1 : 0;

    prep_w32s<<<(36 * 32768) / 256, 256, 0, stream>>>(Wih1, Whh1, l1w);
    prep_w16s<<<(20 * 8 * 2048) / 256, 256, 0, stream>>>(Wih2, Whh2, l2w, 128, 512, 512, 128, 8, 20);
    prep_w16s<<<(6 * 4 * 2048) / 256, 256, 0, stream>>>(Wih3, Whh3, l3w, 64, 128, 128, 64, 4, 6);
    pack_wt1<<<(480 * 1024) / 256, 256, 0, stream>>>(Wf1, WT1);
    pack_wt2<<<(256 * 512) / 256, 256, 0, stream>>>(Wf2, WT2);
    if (xtmode) {
        prep_xt2<<<8192, 256, 0, stream>>>(x1, x2, xt2);
    }

    (void)hipFuncSetAttribute((const void*)lstm3_v11,
                              hipFuncAttributeMaxDynamicSharedMemorySize, 102400);
    lstm3_v11<<<256, 1024, 102400, stream>>>(x1, x2, xt2, xtmode,
                                             l1w, l2w, l3w, b1, b2, b3, dbuf);

    (void)hipFuncSetAttribute((const void*)head_v2,
                              hipFuncAttributeMaxDynamicSharedMemorySize, 16 * 1928 * 4);
    head_v2<<<256, 512, 16 * 1928 * 4, stream>>>(dbuf, WT1, bf1, WT2, bf2,
                                                 Wf3, bf3, Wf4, bf4, out);
}

// Round 10
// 2397.085 us; speedup vs baseline: 1.4261x; 1.4261x over previous
//
#include <hip/hip_runtime.h>

#define NTIME 30
#define NB 4096

typedef __attribute__((ext_vector_type(8))) short short8;
typedef __attribute__((ext_vector_type(8))) _Float16 half8;
typedef __attribute__((ext_vector_type(4))) float f32x4;
typedef __attribute__((ext_vector_type(16))) float f32x16;

__device__ __forceinline__ unsigned short f2h(float f) {
    _Float16 h = (_Float16)f;                  // RNE
    unsigned short u; __builtin_memcpy(&u, &h, 2); return u;
}
__device__ __forceinline__ float h2f(unsigned short u) {
    _Float16 h; __builtin_memcpy(&h, &u, 2); return (float)h;
}
__device__ __forceinline__ half8 s2h8(short8 s) {
    union { short8 s; half8 h; } u; u.s = s; return u.h;
}
__device__ __forceinline__ float sigf(float x)     { return 1.0f / (1.0f + __expf(-x)); }
__device__ __forceinline__ float tanhfast(float x) { return 1.0f - 2.0f / (__expf(2.0f * x) + 1.0f); }

// AGPR-resident carried state. VOLATILE is load-bearing (r9 lesson): at the
// 128-reg wall (16-wave block -> 64 arch + 64 acc), any scheduler freedom on
// these moves extends live ranges and converts directly into scratch spills
// (non-volatile variant tripled WRITE_SIZE to 3.3 GB).
__device__ __forceinline__ float ag_in(float v) {
    float r;
    asm volatile("v_accvgpr_write_b32 %0, %1" : "=a"(r) : "v"(v));
    return r;
}
__device__ __forceinline__ float ag_out(float a) {
    float r;
    asm volatile("v_accvgpr_read_b32 %0, %1" : "=v"(r) : "a"(a));
    return r;
}

// LDS-only barrier: all cross-wave communication inside lstm3 is via LDS, so we
// only need lgkmcnt(0)+s_barrier. Does NOT drain vmcnt -> global weight
// prefetches stay in flight across phase boundaries.
__device__ __forceinline__ void bar_lds() {
    asm volatile("s_waitcnt lgkmcnt(0)" ::: "memory");
    __builtin_amdgcn_s_barrier();
    asm volatile("" ::: "memory");
}

// ---- L1 weight pack: 32x32x16 B-frags, SINGLE fp16 plane.
__global__ __launch_bounds__(256) void prep_w32s(const float* __restrict__ Wih,
                                                 const float* __restrict__ Whh,
                                                 unsigned short* __restrict__ out)
{
    int e = blockIdx.x * 256 + threadIdx.x;
    if (e >= 36 * 32768) return;
    int j    = e & 7;
    int lane = (e >> 3) & 63;
    int g    = (e >> 9) & 3;
    int w    = (e >> 11) & 15;
    int s    = e >> 15;
    int n = lane & 31, kh = lane >> 5;
    int unit = w * 32 + n;
    int k = s * 16 + kh * 8 + j;
    int row = g * 512 + unit;
    float v = 0.0f;
    if (k < 64) { if (k < 58) v = Wih[row * 58 + k]; }
    else        { v = Whh[row * 512 + (k - 64)]; }
    out[e] = f2h(v);
}

// ---- L2/L3 weight pack: 16x16x32 B-frags, single fp16 plane.
__global__ __launch_bounds__(256) void prep_w16s(const float* __restrict__ Wih,
                                                 const float* __restrict__ Whh,
                                                 unsigned short* __restrict__ out,
                                                 int H, int KI, int KIp, int KH, int CG, int KS)
{
    int e = blockIdx.x * 256 + threadIdx.x;
    if (e >= KS * CG * 2048) return;
    int j    = e & 7;
    int lane = (e >> 3) & 63;
    int g    = (e >> 9) & 3;
    int rest = e >> 11;
    int cg = rest % CG;
    int s  = rest / CG;
    int n = lane & 15, q = lane >> 4;
    int unit = cg * 16 + n;
    int k = s * 32 + q * 8 + j;
    int row = g * H + unit;
    float v = 0.0f;
    if (k < KIp) { if (k < KI) v = Wih[row * KI + k]; }
    else         { v = Whh[row * KH + (k - KIp)]; }
    out[e] = f2h(v);
}

// ---- x pre-pack: x[B,F,T] -> fp16 xT2[wg][t][32 rows][64 f] (per-WG LDS
// staging layout; rows 0-15 = x1 samples, 16-31 = x2). Verified correct in r9.
__global__ __launch_bounds__(256) void prep_xt2(const float* __restrict__ x1,
                                                const float* __restrict__ x2,
                                                unsigned short* __restrict__ xT)
{
    __shared__ float tile[1740];
    int blk = blockIdx.x;               // [0, 8192): br*4096 + s
    int br = blk >> 12;
    int s  = blk & 4095;
    const float* xp = (br ? x2 : x1) + (size_t)s * 1740;
    for (int i = threadIdx.x; i < 1740; i += 256) tile[i] = xp[i];
    __syncthreads();
    int wg = s >> 4, row = (br << 4) | (s & 15);
    unsigned short* dst = xT + ((size_t)wg * 30 * 32 + row) * 64;
    for (int i = threadIdx.x; i < 1920; i += 256) {
        int t = i >> 6, f = i & 63;
        dst[(size_t)t * 2048 + f] = f2h((f < 58) ? tile[f * 30 + t] : 0.0f);
    }
}

// ---- Head weight transposes (o-fastest float4 blocks)
__global__ __launch_bounds__(256) void pack_wt1(const float* __restrict__ Wf1, float4* __restrict__ WT1)
{
    int e = blockIdx.x * 256 + threadIdx.x;
    if (e >= 480 * 1024) return;
    int kc = e >> 10, o = e & 1023;
    float4 v = {0.0f, 0.0f, 0.0f, 0.0f};
    if (o < 960) {
        const float* p = Wf1 + (size_t)o * 1920 + kc * 4;
        v.x = p[0]; v.y = p[1]; v.z = p[2]; v.w = p[3];
    }
    WT1[e] = v;
}
__global__ __launch_bounds__(256) void pack_wt2(const float* __restrict__ Wf2, float4* __restrict__ WT2)
{
    int e = blockIdx.x * 256 + threadIdx.x;
    if (e >= 256 * 512) return;
    int kc = e >> 9, o = e & 511;
    float4 v = {0.0f, 0.0f, 0.0f, 0.0f};
    if (o < 480) {
        int k = kc * 4;
        v.x = (k + 0 < 960) ? Wf2[(size_t)o * 960 + k + 0] : 0.0f;
        v.y = (k + 1 < 960) ? Wf2[(size_t)o * 960 + k + 1] : 0.0f;
        v.z = (k + 2 < 960) ? Wf2[(size_t)o * 960 + k + 2] : 0.0f;
        v.w = (k + 3 < 960) ? Wf2[(size_t)o * 960 + k + 3] : 0.0f;
    }
    WT2[e] = v;
}

#define MFMA32(A, X, B) A = __builtin_amdgcn_mfma_f32_32x32x16_f16((X), (B), (A), 0, 0, 0)
#define MFMA16(A, X, B) A = __builtin_amdgcn_mfma_f32_16x16x32_f16((X), (B), (A), 0, 0, 0)

// L1 A-fragment load (x for s<4, h1 otherwise); single-plane fp16 activations.
#define L1_LOAD_A(SV) do { \
    if ((SV) < 4) { \
        a = *(const half8*)(xh + n1 * 72 + (SV) * 16 + kh * 8); \
    } else { \
        a = *(const half8*)(h1b + n1 * 520 + ((SV) - 4) * 16 + kh * 8); \
    } } while (0)

// one L1 k-step of a 2-gate pass (gate byte-offsets GA, GB within a slab):
// 2 MFMAs, depth-3 rotating refill.
#define L1_SUB(WA, WB, IDX, GA, GB) do { \
    const int _s = rev ? (35 - (ss + (IDX))) : (ss + (IDX)); \
    half8 a; \
    L1_LOAD_A(_s); \
    MFMA32(P0, a, WA); \
    MFMA32(P1, a, WB); \
    if (ss + (IDX) + 3 < 36) { \
        const int _sn = rev ? (35 - (ss + (IDX) + 3)) : (ss + (IDX) + 3); \
        const unsigned short* _bb = B1p + _sn * 32768; \
        WA = *(const half8*)(_bb + (GA)); \
        WB = *(const half8*)(_bb + (GB)); \
    } } while (0)

#define L1_KLOOP(GA, GB) \
    _Pragma("unroll 1") \
    for (int ss = 0; ss < 36; ss += 3) { \
        L1_SUB(w0a, w0b, 0, GA, GB); \
        L1_SUB(w1a, w1b, 1, GA, GB); \
        L1_SUB(w2a, w2b, 2, GA, GB); \
    }

// entry prefetch of the first 3 k-steps of a pass. RV = direction of that pass.
#define L1_ENTRY(GA, GB, RV) do { \
    const int _s0 = (RV) ? 35 : 0, _s1 = (RV) ? 34 : 1, _s2 = (RV) ? 33 : 2; \
    const unsigned short* _b0 = B1p + _s0 * 32768; \
    const unsigned short* _b1 = B1p + _s1 * 32768; \
    const unsigned short* _b2 = B1p + _s2 * 32768; \
    w0a = *(const half8*)(_b0 + (GA)); w0b = *(const half8*)(_b0 + (GB)); \
    w1a = *(const half8*)(_b1 + (GA)); w1b = *(const half8*)(_b1 + (GB)); \
    w2a = *(const half8*)(_b2 + (GA)); w2b = *(const half8*)(_b2 + (GB)); \
} while (0)

#define L2_LOAD_A(SV) do { \
    if ((SV) < 16) { \
        short8 _a = *(const short8*)(h1b + row2 * 520 + (SV) * 32 + quad * 8); \
        short8 _msk = _a >> 15; \
        a = s2h8(_a & ~_msk); \
    } else { \
        a = *(const half8*)(h2b + cur * 4352 + row2 * 136 + ((SV) - 16) * 32 + quad * 8); \
    } } while (0)

// one L2 k-step, all 4 gates: 4 MFMAs, depth-2 ping-pong refill.
#define L2_SUB(Q0, Q1, Q2, Q3, IDX) do { \
    const int _s = rev ? (19 - (ss + (IDX))) : (ss + (IDX)); \
    half8 a; \
    L2_LOAD_A(_s); \
    MFMA16(A0, a, Q0); \
    MFMA16(A1, a, Q1); \
    MFMA16(A2, a, Q2); \
    MFMA16(A3, a, Q3); \
    if (ss + (IDX) + 2 < 20) { \
        const int _sn = rev ? (19 - (ss + (IDX) + 2)) : (ss + (IDX) + 2); \
        const unsigned short* _bb = B2p + _sn * 16384; \
        Q0 = *(const half8*)(_bb); \
        Q1 = *(const half8*)(_bb + 512); \
        Q2 = *(const half8*)(_bb + 1024); \
        Q3 = *(const half8*)(_bb + 1536); \
    } } while (0)

#define L2_ENTRY() do { \
    const int _s0 = rev ? 19 : 0, _s1 = rev ? 18 : 1; \
    const unsigned short* _b0 = B2p + _s0 * 16384; \
    const unsigned short* _b1 = B2p + _s1 * 16384; \
    qa0 = *(const half8*)(_b0);        qa1 = *(const half8*)(_b0 + 512); \
    qa2 = *(const half8*)(_b0 + 1024); qa3 = *(const half8*)(_b0 + 1536); \
    qb0 = *(const half8*)(_b1);        qb1 = *(const half8*)(_b1 + 512); \
    qb2 = *(const half8*)(_b1 + 1024); qb3 = *(const half8*)(_b1 + 1536); \
} while (0)

#define L3_LOAD_A(SV) do { \
    if ((SV) < 4) { \
        short8 _a = *(const short8*)(h2b + nxt * 4352 + row3 * 136 + (SV) * 32 + quad * 8); \
        short8 _msk = _a >> 15; \
        a = s2h8(_a & ~_msk); \
    } else { \
        a = *(const half8*)(h3b + cur * 2304 + row3 * 72 + ((SV) - 4) * 32 + quad * 8); \
    } } while (0)

#define L3_SUB(Q0, Q1, Q2, Q3, IDX) do { \
    const int _s = rev ? (5 - (ss + (IDX))) : (ss + (IDX)); \
    half8 a; \
    L3_LOAD_A(_s); \
    MFMA16(A0, a, Q0); \
    MFMA16(A1, a, Q1); \
    MFMA16(A2, a, Q2); \
    MFMA16(A3, a, Q3); \
    if (ss + (IDX) + 2 < 6) { \
        const int _sn = rev ? (5 - (ss + (IDX) + 2)) : (ss + (IDX) + 2); \
        const unsigned short* _bb = B3p + _sn * 8192; \
        Q0 = *(const half8*)(_bb); \
        Q1 = *(const half8*)(_bb + 512); \
        Q2 = *(const half8*)(_bb + 1024); \
        Q3 = *(const half8*)(_bb + 1536); \
    } } while (0)

#define L3_ENTRY_A() do { \
    const int _s0 = rev ? 5 : 0; \
    const unsigned short* _b0 = B3p + _s0 * 8192; \
    ra0 = *(const half8*)(_b0);        ra1 = *(const half8*)(_b0 + 512); \
    ra2 = *(const half8*)(_b0 + 1024); ra3 = *(const half8*)(_b0 + 1536); \
} while (0)

#define L3_ENTRY_B() do { \
    const int _s1 = rev ? 4 : 1; \
    const unsigned short* _b1 = B3p + _s1 * 8192; \
    rb0 = *(const half8*)(_b1);        rb1 = *(const half8*)(_b1 + 512); \
    rb2 = *(const half8*)(_b1 + 1024); rb3 = *(const half8*)(_b1 + 1536); \
} while (0)

// ---- Fused Siamese 3-layer LSTM. 256 WGs x 1024 thr (16 waves, 4/SIMD), 69KB LDS.
// Round-19 (v12): v9 verbatim (best verified: lstm 1794us) + ONE delta: the
// verified-correct xt2 fp16 pre-pack staging from r9. In-loop x staging is now
// 2 coalesced ushort loads + 2 LDS stores per thread (was 2 f32 loads + 2 f2h).
// Reverted from r9's regression bundle: volatile AGPR moves restored, single
// h1 buffer restored, barrier B restored (the non-volatile/h1-dbuf combo
// tripled spills at the 128-reg wall).
__global__ __launch_bounds__(1024, 4) void lstm3_v12(
    const float* __restrict__ x1, const float* __restrict__ x2,
    const unsigned short* __restrict__ xt2, const int xtmode,
    const unsigned short* __restrict__ l1w, const unsigned short* __restrict__ l2w,
    const unsigned short* __restrict__ l3w,
    const float* __restrict__ b1, const float* __restrict__ b2, const float* __restrict__ b3,
    float* __restrict__ dbuf)
{
    extern __shared__ unsigned short sm[];
    unsigned short* h1b = sm;                    // [32][520]
    unsigned short* h2b = h1b + 32 * 520;        // [2][32][136]
    unsigned short* h3b = h2b + 2 * 32 * 136;    // [2][32][72]
    unsigned short* xb  = h3b + 2 * 32 * 72;     // [2][32][72] double-buffered
    // total 34560 shorts = 69120 B

    const int tid  = threadIdx.x;
    const int wv   = tid >> 6;
    const int lane = tid & 63;
    const int wg   = blockIdx.x;
    const int samp0 = wg * 16;

    {
        unsigned int* p = (unsigned int*)sm;
        for (int i = tid; i < 17280; i += 1024) p[i] = 0u;
    }

    // L1 lane mapping (32x32)
    const int n1 = lane & 31;
    const int kh = lane >> 5;
    const int u1 = wv * 32 + n1;
    // L2/L3 lane mapping (16x16)
    const int n2   = lane & 15;
    const int quad = lane >> 4;
    const int mt2  = wv >> 3, cg2 = wv & 7;
    const int u2   = cg2 * 16 + n2;
    const int row2 = mt2 * 16 + n2;
    const int mt3  = (wv >> 2) & 1, cg3 = wv & 3;
    const int u3   = cg3 * 16 + n2;
    const int row3 = mt3 * 16 + n2;

    // carried state, AGPR-resident
    float c1a[16], iga[16], c2a[4], c3a[4];
    #pragma unroll
    for (int r = 0; r < 16; ++r) { c1a[r] = ag_in(0.0f); iga[r] = ag_in(0.0f); }
    #pragma unroll
    for (int r = 0; r < 4; ++r) { c2a[r] = ag_in(0.0f); c3a[r] = ag_in(0.0f); }

    const unsigned short* B1p = l1w + wv * 2048 + lane * 8;
    const unsigned short* B2p = l2w + cg2 * 2048 + lane * 8;
    const unsigned short* B3p = l3w + cg3 * 2048 + lane * 8;

    // register pools
    half8 w0a, w0b, w1a, w1b, w2a, w2b;             // L1 rotation (24 VGPR)
    half8 qa0, qa1, qa2, qa3, qb0, qb1, qb2, qb3;   // L2 ping-pong (32 VGPR)
    half8 ra0, ra1, ra2, ra3, rb0, rb1, rb2, rb3;   // L3 ping-pong (32 VGPR)

    // t=0 pass0 entry prefetch (fwd direction, gates i,g at offsets 0,1024)
    L1_ENTRY(0, 1024, false);

    // stage x_0 into parity-0 buffer (prologue; covers all 32 rows)
    for (int e = tid; e < 2048; e += 1024) {
        int b = e >> 6, f = e & 63;
        if (xtmode) {
            xb[b * 72 + f] = xt2[(((size_t)wg * 30 + 0) * 32 + b) * 64 + f];
        } else {
            const float* __restrict__ xp = (b < 16) ? x1 : x2;
            float v = (f < 58) ? xp[(samp0 + (b & 15)) * 1740 + f * 30 + 0] : 0.0f;
            xb[b * 72 + f] = f2h(v);
        }
    }
    bar_lds();

    int cur = 0;
    #pragma unroll 1
    for (int t = 0; t < NTIME; ++t) {
        const bool rev = (t & 1);
        const int nxt = cur ^ 1;
        const unsigned short* xh = xb + (t & 1) * 2304;

        // ===== L1 pass 0: gates i,g -> ig = sig(i)*tanh(g), AGPR-resident =====
        {
            f32x16 P0, P1;
            #pragma unroll
            for (int r = 0; r < 16; ++r) { P0[r] = 0.0f; P1[r] = 0.0f; }
            float bgi = b1[u1], bgg = b1[1024 + u1];
            L1_KLOOP(0, 1024);
            L1_ENTRY(512, 1536, rev);     // pass1 entry (gates f,o), hides under epilogue
            #pragma unroll
            for (int r = 0; r < 16; ++r) {
                iga[r] = ag_in(sigf(P0[r] + bgi) * tanhfast(P1[r] + bgg));
            }
        }
        // ===== L1 pass 1: gates f,o -> cell update + h =====
        {
            f32x16 P0, P1;
            #pragma unroll
            for (int r = 0; r < 16; ++r) { P0[r] = 0.0f; P1[r] = 0.0f; }
            float bgf = b1[512 + u1], bgo = b1[1536 + u1];
            L1_KLOOP(512, 1536);
            bar_lds();   // B: all reads of h1(t-1)/x(t) done
            #pragma unroll
            for (int r = 0; r < 16; ++r) {
                float F = sigf(P0[r] + bgf);
                float O = sigf(P1[r] + bgo);
                float c = F * ag_out(c1a[r]) + ag_out(iga[r]);
                c1a[r] = ag_in(c);
                float h = O * tanhfast(c);
                int row = (r & 3) + 8 * (r >> 2) + 4 * kh;   // verified 32x32 C-map
                h1b[row * 520 + u1] = f2h(h);
            }
        }
        bar_lds();   // C: h1(t) visible

        // x(t+1): issue the coalesced global loads (both branches) first, then L2
        // weight entry, LDS writes last.
        unsigned short xv16a = 0, xv16b = 0;
        float xv0 = 0.0f, xv1 = 0.0f;
        if (t + 1 < NTIME) {
            int b = tid >> 6, f = tid & 63;
            if (xtmode) {
                const unsigned short* p = xt2 + (((size_t)wg * 30 + (t + 1)) * 32 + b) * 64 + f;
                xv16a = p[0];
                xv16b = p[16 * 64];    // x2 branch rows (16..31)
            } else {
                int idx = (samp0 + b) * 1740 + f * 30 + (t + 1);
                xv0 = (f < 58) ? x1[idx] : 0.0f;
                xv1 = (f < 58) ? x2[idx] : 0.0f;
            }
        }

        L2_ENTRY();   // L2 entry frags (overlaps x write)

        if (t + 1 < NTIME) {
            unsigned short* xb2 = xb + ((t + 1) & 1) * 2304;
            int b = tid >> 6, f = tid & 63;
            if (xtmode) {
                xb2[b * 72 + f] = xv16a;
                xb2[(16 + b) * 72 + f] = xv16b;
            } else {
                xb2[b * 72 + f] = f2h(xv0);
                xb2[(16 + b) * 72 + f] = f2h(xv1);
            }
        }

        // ===== L2: single 4-gate pass; k = [relu(h1) 512 | h2 128], 20 ksteps =====
        {
            f32x4 A0 = {0.0f, 0.0f, 0.0f, 0.0f};
            f32x4 A1 = {0.0f, 0.0f, 0.0f, 0.0f};
            f32x4 A2 = {0.0f, 0.0f, 0.0f, 0.0f};
            f32x4 A3 = {0.0f, 0.0f, 0.0f, 0.0f};
            float bg0 = b2[u2], bg1 = b2[128 + u2], bg2 = b2[256 + u2], bg3 = b2[384 + u2];
            #pragma unroll 1
            for (int ss = 0; ss < 20; ss += 2) {
                L2_SUB(qa0, qa1, qa2, qa3, 0);
                L2_SUB(qb0, qb1, qb2, qb3, 1);
            }
            if (wv < 8) { L3_ENTRY_A(); }   // only set A (16 regs) across bar D
            #pragma unroll
            for (int r = 0; r < 4; ++r) {
                float I = sigf(A0[r] + bg0);
                float F = sigf(A1[r] + bg1);
                float G = tanhfast(A2[r] + bg2);
                float O = sigf(A3[r] + bg3);
                float c = F * ag_out(c2a[r]) + I * G;
                c2a[r] = ag_in(c);
                float h = O * tanhfast(c);
                int row = mt2 * 16 + quad * 4 + r;
                h2b[nxt * 4352 + row * 136 + u2] = f2h(h);
            }
        }
        bar_lds();   // D: h2(t) + x(t+1) visible

        // ===== L3: single 4-gate pass; k = [relu(h2) 128 | h3 64], 6 ksteps, waves 0-7 =====
        if (wv < 8) {
            f32x4 A0 = {0.0f, 0.0f, 0.0f, 0.0f};
            f32x4 A1 = {0.0f, 0.0f, 0.0f, 0.0f};
            f32x4 A2 = {0.0f, 0.0f, 0.0f, 0.0f};
            f32x4 A3 = {0.0f, 0.0f, 0.0f, 0.0f};
            float bg0 = b3[u3], bg1 = b3[64 + u3], bg2 = b3[128 + u3], bg3 = b3[192 + u3];
            L3_ENTRY_B();   // set B fetched post-barrier, covered by first L3_SUB
            #pragma unroll 1
            for (int ss = 0; ss < 6; ss += 2) {
                L3_SUB(ra0, ra1, ra2, ra3, 0);
                L3_SUB(rb0, rb1, rb2, rb3, 1);
            }
            #pragma unroll
            for (int r = 0; r < 4; ++r) {
                float I = sigf(A0[r] + bg0);
                float F = sigf(A1[r] + bg1);
                float G = tanhfast(A2[r] + bg2);
                float O = sigf(A3[r] + bg3);
                float c = F * ag_out(c3a[r]) + I * G;
                c3a[r] = ag_in(c);
                float h = O * tanhfast(c);
                int row = mt3 * 16 + quad * 4 + r;
                h3b[nxt * 2304 + row * 72 + u3] = f2h(h);
            }
        }

        // next-t pass0 entry prefetch: issued before bar E + d-write, survives the
        // backedge (LDS-only barriers keep vmcnt).
        if (t + 1 < NTIME) {
            L1_ENTRY(0, 1024, !rev);
        }
        bar_lds();   // E: h3(t) visible

        // d = |relu(h3_x1) - relu(h3_x2)| -> global
        {
            int b = tid >> 6, u = tid & 63;
            float ha = h2f(h3b[nxt * 2304 + b * 72 + u]);
            float hb = h2f(h3b[nxt * 2304 + (16 + b) * 72 + u]);
            dbuf[(size_t)(samp0 + b) * 1920 + t * 64 + u] = fabsf(fmaxf(ha, 0.0f) - fmaxf(hb, 0.0f));
        }
        cur = nxt;
    }
}

// ---- FC head v2
__global__ __launch_bounds__(512) void head_v2(
    const float* __restrict__ dg,
    const float4* __restrict__ WT1, const float* __restrict__ bf1,
    const float4* __restrict__ WT2, const float* __restrict__ bf2,
    const float* __restrict__ Wf3, const float* __restrict__ bf3,
    const float* __restrict__ Wf4, const float* __restrict__ bf4,
    float* __restrict__ out)
{
    extern __shared__ float hds[];
    float* ds = hds;                  // [16][1928] during fc1
    float* a1 = hds;                  // [16][1032] overlay after fc1
    float* a2 = a1 + 16 * 1032;       // [16][520]
    float* a3 = a2 + 16 * 520;        // [16][16]

    const int tid = threadIdx.x;
    const int samp0 = blockIdx.x * 16;

    for (int e = tid; e < 16 * 480; e += 512) {
        int b = e / 480, jc = e - b * 480;
        const float* src = dg + (size_t)(samp0 + b) * 1920 + jc * 4;
        float* dst = ds + b * 1928 + jc * 4;
        dst[0] = src[0]; dst[1] = src[1]; dst[2] = src[2]; dst[3] = src[3];
    }
    __syncthreads();

    const int w = tid >> 6, lane = tid & 63;
    const int oA = w * 128 + lane, oB = oA + 64;
    float accA[16], accB[16];
    {
        float bA = (oA < 960) ? bf1[oA] : 0.0f;
        float bB = (oB < 960) ? bf1[oB] : 0.0f;
        #pragma unroll
        for (int r = 0; r < 16; ++r) { accA[r] = bA; accB[r] = bB; }
    }
    #pragma unroll 2
    for (int kc = 0; kc < 480; ++kc) {
        float4 wA = WT1[kc * 1024 + oA];
        float4 wB = WT1[kc * 1024 + oB];
        #pragma unroll
        for (int r = 0; r < 16; ++r) {
            float4 d4 = ((const float4*)(ds + r * 1928))[kc];
            accA[r] += d4.x * wA.x + d4.y * wA.y + d4.z * wA.z + d4.w * wA.w;
            accB[r] += d4.x * wB.x + d4.y * wB.y + d4.z * wB.z + d4.w * wB.w;
        }
    }
    __syncthreads();
    #pragma unroll
    for (int r = 0; r < 16; ++r) {
        a1[r * 1032 + oA] = fmaxf(accA[r], 0.0f);
        a1[r * 1032 + oB] = fmaxf(accB[r], 0.0f);
    }
    __syncthreads();

    const int o2 = tid;
    float acc2[16];
    {
        float b = (o2 < 480) ? bf2[o2] : 0.0f;
        #pragma unroll
        for (int r = 0; r < 16; ++r) acc2[r] = b;
    }
    #pragma unroll 2
    for (int kc = 0; kc < 256; ++kc) {
        float4 w4 = WT2[kc * 512 + o2];
        #pragma unroll
        for (int r = 0; r < 16; ++r) {
            float4 a4 = ((const float4*)(a1 + r * 1032))[kc];
            acc2[r] += a4.x * w4.x + a4.y * w4.y + a4.z * w4.z + a4.w * w4.w;
        }
    }
    #pragma unroll
    for (int r = 0; r < 16; ++r) a2[r * 520 + o2] = fmaxf(acc2[r], 0.0f);
    __syncthreads();

    if (tid < 256) {
        int o = tid & 15, r = tid >> 4;
        float acc = bf3[o];
        const float4* wr = (const float4*)(Wf3 + (size_t)o * 480);
        const float4* av = (const float4*)(a2 + r * 520);
        #pragma unroll 4
        for (int kc = 0; kc < 120; ++kc) {
            float4 a4 = av[kc];
            float4 w4 = wr[kc];
            acc += a4.x * w4.x + a4.y * w4.y + a4.z * w4.z + a4.w * w4.w;
        }
        a3[r * 16 + o] = fmaxf(acc, 0.0f);
    }
    __syncthreads();

    if (tid < 16) {
        float acc = bf4[0];
        #pragma unroll
        for (int k = 0; k < 16; ++k) acc += a3[tid * 16 + k] * Wf4[k];
        out[samp0 + tid] = acc;
    }
}

extern "C" void kernel_launch(void* const* d_in, const int* in_sizes, int n_in,
                              void* d_out, int out_size, void* d_ws, size_t ws_size,
                              hipStream_t stream) {
    const float* x1   = (const float*)d_in[0];
    const float* x2   = (const float*)d_in[1];
    const float* Wih1 = (const float*)d_in[2];
    const float* Whh1 = (const float*)d_in[3];
    const float* b1   = (const float*)d_in[4];
    const float* Wih2 = (const float*)d_in[5];
    const float* Whh2 = (const float*)d_in[6];
    const float* b2   = (const float*)d_in[7];
    const float* Wih3 = (const float*)d_in[8];
    const float* Whh3 = (const float*)d_in[9];
    const float* b3   = (const float*)d_in[10];
    const float* Wf1  = (const float*)d_in[11];
    const float* bf1  = (const float*)d_in[12];
    const float* Wf2  = (const float*)d_in[13];
    const float* bf2  = (const float*)d_in[14];
    const float* Wf3  = (const float*)d_in[15];
    const float* bf3  = (const float*)d_in[16];
    const float* Wf4  = (const float*)d_in[17];
    const float* bf4  = (const float*)d_in[18];

    float* wsf = (float*)d_ws;
    float* dbuf = wsf;                                         // 4096*1920 = 7,864,320 f32
    unsigned short* l1w = (unsigned short*)(wsf + 7864320);    // 36*32768 = 1,179,648 us
    unsigned short* l2w = l1w + 1179648;                       // 20*8*2048 =  327,680 us
    unsigned short* l3w = l2w + 327680;                        //  6*4*2048 =   49,152 us
    float4* WT1 = (float4*)(wsf + 8642560);                    // 480*1024 float4
    float4* WT2 = WT1 + 480 * 1024;                            // 256*512  float4
    unsigned short* xt2 = (unsigned short*)(wsf + 11132928);   // 256*30*32*64 = 15,728,640 us
    float* out = (float*)d_out;

    const size_t need_bytes = (size_t)11132928 * 4u + (size_t)15728640 * 2u;
    const int xtmode = (ws_size >= need_bytes) ? 1 : 0;

    prep_w32s<<<(36 * 32768) / 256, 256, 0, stream>>>(Wih1, Whh1, l1w);
    prep_w16s<<<(20 * 8 * 2048) / 256, 256, 0, stream>>>(Wih2, Whh2, l2w, 128, 512, 512, 128, 8, 20);
    prep_w16s<<<(6 * 4 * 2048) / 256, 256, 0, stream>>>(Wih3, Whh3, l3w, 64, 128, 128, 64, 4, 6);
    pack_wt1<<<(480 * 1024) / 256, 256, 0, stream>>>(Wf1, WT1);
    pack_wt2<<<(256 * 512) / 256, 256, 0, stream>>>(Wf2, WT2);
    if (xtmode) {
        prep_xt2<<<8192, 256, 0, stream>>>(x1, x2, xt2);
    }

    (void)hipFuncSetAttribute((const void*)lstm3_v12,
                              hipFuncAttributeMaxDynamicSharedMemorySize, 69120);
    lstm3_v12<<<256, 1024, 69120, stream>>>(x1, x2, xt2, xtmode,
                                            l1w, l2w, l3w, b1, b2, b3, dbuf);

    (void)hipFuncSetAttribute((const void*)head_v2,
                              hipFuncAttributeMaxDynamicSharedMemorySize, 16 * 1928 * 4);
    head_v2<<<256, 512, 16 * 1928 * 4, stream>>>(dbuf, WT1, bf1, WT2, bf2,
                                                 Wf3, bf3, Wf4, bf4, out);
}

// Round 11
// 1852.606 us; speedup vs baseline: 1.8452x; 1.2939x over previous
//
#include <hip/hip_runtime.h>

#define NTIME 30
#define NB 4096

typedef __attribute__((ext_vector_type(8))) short short8;
typedef __attribute__((ext_vector_type(8))) _Float16 half8;
typedef __attribute__((ext_vector_type(4))) float f32x4;
typedef __attribute__((ext_vector_type(16))) float f32x16;

__device__ __forceinline__ unsigned short f2h(float f) {
    _Float16 h = (_Float16)f;                  // RNE
    unsigned short u; __builtin_memcpy(&u, &h, 2); return u;
}
__device__ __forceinline__ float h2f(unsigned short u) {
    _Float16 h; __builtin_memcpy(&h, &u, 2); return (float)h;
}
__device__ __forceinline__ half8 s2h8(short8 s) {
    union { short8 s; half8 h; } u; u.s = s; return u.h;
}
__device__ __forceinline__ float sigf(float x)     { return 1.0f / (1.0f + __expf(-x)); }
__device__ __forceinline__ float tanhfast(float x) { return 1.0f - 2.0f / (__expf(2.0f * x) + 1.0f); }

// AGPR-resident carried state. VOLATILE is load-bearing (r9 lesson): at the
// 128-reg wall, scheduler freedom on these moves converts into scratch spills.
__device__ __forceinline__ float ag_in(float v) {
    float r;
    asm volatile("v_accvgpr_write_b32 %0, %1" : "=a"(r) : "v"(v));
    return r;
}
__device__ __forceinline__ float ag_out(float a) {
    float r;
    asm volatile("v_accvgpr_read_b32 %0, %1" : "=v"(r) : "a"(a));
    return r;
}

// LDS-only barrier: does NOT drain vmcnt -> weight prefetches stay in flight.
__device__ __forceinline__ void bar_lds() {
    asm volatile("s_waitcnt lgkmcnt(0)" ::: "memory");
    __builtin_amdgcn_s_barrier();
    asm volatile("" ::: "memory");
}

// ---- L1 weight pack: 32x32x16 B-frags, SINGLE fp16 plane.
__global__ __launch_bounds__(256) void prep_w32s(const float* __restrict__ Wih,
                                                 const float* __restrict__ Whh,
                                                 unsigned short* __restrict__ out)
{
    int e = blockIdx.x * 256 + threadIdx.x;
    if (e >= 36 * 32768) return;
    int j    = e & 7;
    int lane = (e >> 3) & 63;
    int g    = (e >> 9) & 3;
    int w    = (e >> 11) & 15;
    int s    = e >> 15;
    int n = lane & 31, kh = lane >> 5;
    int unit = w * 32 + n;
    int k = s * 16 + kh * 8 + j;
    int row = g * 512 + unit;
    float v = 0.0f;
    if (k < 64) { if (k < 58) v = Wih[row * 58 + k]; }
    else        { v = Whh[row * 512 + (k - 64)]; }
    out[e] = f2h(v);
}

// ---- L2/L3 weight pack: 16x16x32 B-frags, single fp16 plane.
__global__ __launch_bounds__(256) void prep_w16s(const float* __restrict__ Wih,
                                                 const float* __restrict__ Whh,
                                                 unsigned short* __restrict__ out,
                                                 int H, int KI, int KIp, int KH, int CG, int KS)
{
    int e = blockIdx.x * 256 + threadIdx.x;
    if (e >= KS * CG * 2048) return;
    int j    = e & 7;
    int lane = (e >> 3) & 63;
    int g    = (e >> 9) & 3;
    int rest = e >> 11;
    int cg = rest % CG;
    int s  = rest / CG;
    int n = lane & 15, q = lane >> 4;
    int unit = cg * 16 + n;
    int k = s * 32 + q * 8 + j;
    int row = g * H + unit;
    float v = 0.0f;
    if (k < KIp) { if (k < KI) v = Wih[row * KI + k]; }
    else         { v = Whh[row * KH + (k - KIp)]; }
    out[e] = f2h(v);
}

// ---- head fc1 weight pack: Wf1[960,1920] f32 -> fp16 16x16x32 B-frags.
// Layout [s(60)][cg(60)][lane(64)][j(8)]: col = cg*16+(lane&15), k = s*32+(lane>>4)*8+j.
// Same convention as prep_w16s (validated by L2/L3).  3.7 MB -> per-XCD L2 resident.
__global__ __launch_bounds__(256) void prep_hw1(const float* __restrict__ Wf1,
                                                unsigned short* __restrict__ out)
{
    int e = blockIdx.x * 256 + threadIdx.x;
    if (e >= 60 * 60 * 512) return;
    int j    = e & 7;
    int lane = (e >> 3) & 63;
    int idx  = e >> 9;
    int s  = idx / 60;
    int cg = idx % 60;
    int col = cg * 16 + (lane & 15);
    int k   = s * 32 + (lane >> 4) * 8 + j;
    out[e] = f2h(Wf1[(size_t)col * 1920 + k]);
}

// ---- head fc2 weight pack: Wf2[480,960] -> fp16 B-frags [s(30)][cg(30)][lane][j].
__global__ __launch_bounds__(256) void prep_hw2(const float* __restrict__ Wf2,
                                                unsigned short* __restrict__ out)
{
    int e = blockIdx.x * 256 + threadIdx.x;
    if (e >= 30 * 30 * 512) return;
    int j    = e & 7;
    int lane = (e >> 3) & 63;
    int idx  = e >> 9;
    int s  = idx / 30;
    int cg = idx % 30;
    int col = cg * 16 + (lane & 15);
    int k   = s * 32 + (lane >> 4) * 8 + j;
    out[e] = f2h(Wf2[(size_t)col * 960 + k]);
}

// ---- x pre-pack: x[B,F,T] -> fp16 xT2[wg][t][32 rows][64 f] (per-WG LDS layout).
__global__ __launch_bounds__(256) void prep_xt2(const float* __restrict__ x1,
                                                const float* __restrict__ x2,
                                                unsigned short* __restrict__ xT)
{
    __shared__ float tile[1740];
    int blk = blockIdx.x;               // [0, 8192): br*4096 + s
    int br = blk >> 12;
    int s  = blk & 4095;
    const float* xp = (br ? x2 : x1) + (size_t)s * 1740;
    for (int i = threadIdx.x; i < 1740; i += 256) tile[i] = xp[i];
    __syncthreads();
    int wg = s >> 4, row = (br << 4) | (s & 15);
    unsigned short* dst = xT + ((size_t)wg * 30 * 32 + row) * 64;
    for (int i = threadIdx.x; i < 1920; i += 256) {
        int t = i >> 6, f = i & 63;
        dst[(size_t)t * 2048 + f] = f2h((f < 58) ? tile[f * 30 + t] : 0.0f);
    }
}

#define MFMA32(A, X, B) A = __builtin_amdgcn_mfma_f32_32x32x16_f16((X), (B), (A), 0, 0, 0)
#define MFMA16(A, X, B) A = __builtin_amdgcn_mfma_f32_16x16x32_f16((X), (B), (A), 0, 0, 0)

// L1 A-fragment load (x for s<4, h1 otherwise); single-plane fp16 activations.
#define L1_LOAD_A(SV) do { \
    if ((SV) < 4) { \
        a = *(const half8*)(xh + n1 * 72 + (SV) * 16 + kh * 8); \
    } else { \
        a = *(const half8*)(h1b + n1 * 520 + ((SV) - 4) * 16 + kh * 8); \
    } } while (0)

#define L1_SUB(WA, WB, IDX, GA, GB) do { \
    const int _s = rev ? (35 - (ss + (IDX))) : (ss + (IDX)); \
    half8 a; \
    L1_LOAD_A(_s); \
    MFMA32(P0, a, WA); \
    MFMA32(P1, a, WB); \
    if (ss + (IDX) + 3 < 36) { \
        const int _sn = rev ? (35 - (ss + (IDX) + 3)) : (ss + (IDX) + 3); \
        const unsigned short* _bb = B1p + _sn * 32768; \
        WA = *(const half8*)(_bb + (GA)); \
        WB = *(const half8*)(_bb + (GB)); \
    } } while (0)

#define L1_KLOOP(GA, GB) \
    _Pragma("unroll 1") \
    for (int ss = 0; ss < 36; ss += 3) { \
        L1_SUB(w0a, w0b, 0, GA, GB); \
        L1_SUB(w1a, w1b, 1, GA, GB); \
        L1_SUB(w2a, w2b, 2, GA, GB); \
    }

#define L1_ENTRY(GA, GB, RV) do { \
    const int _s0 = (RV) ? 35 : 0, _s1 = (RV) ? 34 : 1, _s2 = (RV) ? 33 : 2; \
    const unsigned short* _b0 = B1p + _s0 * 32768; \
    const unsigned short* _b1 = B1p + _s1 * 32768; \
    const unsigned short* _b2 = B1p + _s2 * 32768; \
    w0a = *(const half8*)(_b0 + (GA)); w0b = *(const half8*)(_b0 + (GB)); \
    w1a = *(const half8*)(_b1 + (GA)); w1b = *(const half8*)(_b1 + (GB)); \
    w2a = *(const half8*)(_b2 + (GA)); w2b = *(const half8*)(_b2 + (GB)); \
} while (0)

#define L2_LOAD_A(SV) do { \
    if ((SV) < 16) { \
        short8 _a = *(const short8*)(h1b + row2 * 520 + (SV) * 32 + quad * 8); \
        short8 _msk = _a >> 15; \
        a = s2h8(_a & ~_msk); \
    } else { \
        a = *(const half8*)(h2b + cur * 4352 + row2 * 136 + ((SV) - 16) * 32 + quad * 8); \
    } } while (0)

#define L2_SUB(Q0, Q1, Q2, Q3, IDX) do { \
    const int _s = rev ? (19 - (ss + (IDX))) : (ss + (IDX)); \
    half8 a; \
    L2_LOAD_A(_s); \
    MFMA16(A0, a, Q0); \
    MFMA16(A1, a, Q1); \
    MFMA16(A2, a, Q2); \
    MFMA16(A3, a, Q3); \
    if (ss + (IDX) + 2 < 20) { \
        const int _sn = rev ? (19 - (ss + (IDX) + 2)) : (ss + (IDX) + 2); \
        const unsigned short* _bb = B2p + _sn * 16384; \
        Q0 = *(const half8*)(_bb); \
        Q1 = *(const half8*)(_bb + 512); \
        Q2 = *(const half8*)(_bb + 1024); \
        Q3 = *(const half8*)(_bb + 1536); \
    } } while (0)

#define L2_ENTRY() do { \
    const int _s0 = rev ? 19 : 0, _s1 = rev ? 18 : 1; \
    const unsigned short* _b0 = B2p + _s0 * 16384; \
    const unsigned short* _b1 = B2p + _s1 * 16384; \
    qa0 = *(const half8*)(_b0);        qa1 = *(const half8*)(_b0 + 512); \
    qa2 = *(const half8*)(_b0 + 1024); qa3 = *(const half8*)(_b0 + 1536); \
    qb0 = *(const half8*)(_b1);        qb1 = *(const half8*)(_b1 + 512); \
    qb2 = *(const half8*)(_b1 + 1024); qb3 = *(const half8*)(_b1 + 1536); \
} while (0)

#define L3_LOAD_A(SV) do { \
    if ((SV) < 4) { \
        short8 _a = *(const short8*)(h2b + nxt * 4352 + row3 * 136 + (SV) * 32 + quad * 8); \
        short8 _msk = _a >> 15; \
        a = s2h8(_a & ~_msk); \
    } else { \
        a = *(const half8*)(h3b + cur * 2304 + row3 * 72 + ((SV) - 4) * 32 + quad * 8); \
    } } while (0)

#define L3_SUB(Q0, Q1, Q2, Q3, IDX) do { \
    const int _s = rev ? (5 - (ss + (IDX))) : (ss + (IDX)); \
    half8 a; \
    L3_LOAD_A(_s); \
    MFMA16(A0, a, Q0); \
    MFMA16(A1, a, Q1); \
    MFMA16(A2, a, Q2); \
    MFMA16(A3, a, Q3); \
    if (ss + (IDX) + 2 < 6) { \
        const int _sn = rev ? (5 - (ss + (IDX) + 2)) : (ss + (IDX) + 2); \
        const unsigned short* _bb = B3p + _sn * 8192; \
        Q0 = *(const half8*)(_bb); \
        Q1 = *(const half8*)(_bb + 512); \
        Q2 = *(const half8*)(_bb + 1024); \
        Q3 = *(const half8*)(_bb + 1536); \
    } } while (0)

#define L3_ENTRY_A() do { \
    const int _s0 = rev ? 5 : 0; \
    const unsigned short* _b0 = B3p + _s0 * 8192; \
    ra0 = *(const half8*)(_b0);        ra1 = *(const half8*)(_b0 + 512); \
    ra2 = *(const half8*)(_b0 + 1024); ra3 = *(const half8*)(_b0 + 1536); \
} while (0)

#define L3_ENTRY_B() do { \
    const int _s1 = rev ? 4 : 1; \
    const unsigned short* _b1 = B3p + _s1 * 8192; \
    rb0 = *(const half8*)(_b1);        rb1 = *(const half8*)(_b1 + 512); \
    rb2 = *(const half8*)(_b1 + 1024); rb3 = *(const half8*)(_b1 + 1536); \
} while (0)

// ---- Fused Siamese 3-layer LSTM. Round-20 (v13): identical to v12 (verified
// best, lstm 1781us) except dbuf is written as fp16 (feeds the new MFMA head;
// halves d-traffic on both sides).
__global__ __launch_bounds__(1024, 4) void lstm3_v13(
    const float* __restrict__ x1, const float* __restrict__ x2,
    const unsigned short* __restrict__ xt2, const int xtmode,
    const unsigned short* __restrict__ l1w, const unsigned short* __restrict__ l2w,
    const unsigned short* __restrict__ l3w,
    const float* __restrict__ b1, const float* __restrict__ b2, const float* __restrict__ b3,
    unsigned short* __restrict__ dbuf)
{
    extern __shared__ unsigned short sm[];
    unsigned short* h1b = sm;                    // [32][520]
    unsigned short* h2b = h1b + 32 * 520;        // [2][32][136]
    unsigned short* h3b = h2b + 2 * 32 * 136;    // [2][32][72]
    unsigned short* xb  = h3b + 2 * 32 * 72;     // [2][32][72] double-buffered

    const int tid  = threadIdx.x;
    const int wv   = tid >> 6;
    const int lane = tid & 63;
    const int wg   = blockIdx.x;
    const int samp0 = wg * 16;

    {
        unsigned int* p = (unsigned int*)sm;
        for (int i = tid; i < 17280; i += 1024) p[i] = 0u;
    }

    const int n1 = lane & 31;
    const int kh = lane >> 5;
    const int u1 = wv * 32 + n1;
    const int n2   = lane & 15;
    const int quad = lane >> 4;
    const int mt2  = wv >> 3, cg2 = wv & 7;
    const int u2   = cg2 * 16 + n2;
    const int row2 = mt2 * 16 + n2;
    const int mt3  = (wv >> 2) & 1, cg3 = wv & 3;
    const int u3   = cg3 * 16 + n2;
    const int row3 = mt3 * 16 + n2;

    float c1a[16], iga[16], c2a[4], c3a[4];
    #pragma unroll
    for (int r = 0; r < 16; ++r) { c1a[r] = ag_in(0.0f); iga[r] = ag_in(0.0f); }
    #pragma unroll
    for (int r = 0; r < 4; ++r) { c2a[r] = ag_in(0.0f); c3a[r] = ag_in(0.0f); }

    const unsigned short* B1p = l1w + wv * 2048 + lane * 8;
    const unsigned short* B2p = l2w + cg2 * 2048 + lane * 8;
    const unsigned short* B3p = l3w + cg3 * 2048 + lane * 8;

    half8 w0a, w0b, w1a, w1b, w2a, w2b;
    half8 qa0, qa1, qa2, qa3, qb0, qb1, qb2, qb3;
    half8 ra0, ra1, ra2, ra3, rb0, rb1, rb2, rb3;

    L1_ENTRY(0, 1024, false);

    for (int e = tid; e < 2048; e += 1024) {
        int b = e >> 6, f = e & 63;
        if (xtmode) {
            xb[b * 72 + f] = xt2[(((size_t)wg * 30 + 0) * 32 + b) * 64 + f];
        } else {
            const float* __restrict__ xp = (b < 16) ? x1 : x2;
            float v = (f < 58) ? xp[(samp0 + (b & 15)) * 1740 + f * 30 + 0] : 0.0f;
            xb[b * 72 + f] = f2h(v);
        }
    }
    bar_lds();

    int cur = 0;
    #pragma unroll 1
    for (int t = 0; t < NTIME; ++t) {
        const bool rev = (t & 1);
        const int nxt = cur ^ 1;
        const unsigned short* xh = xb + (t & 1) * 2304;

        // ===== L1 pass 0: gates i,g -> ig = sig(i)*tanh(g), AGPR-resident =====
        {
            f32x16 P0, P1;
            #pragma unroll
            for (int r = 0; r < 16; ++r) { P0[r] = 0.0f; P1[r] = 0.0f; }
            float bgi = b1[u1], bgg = b1[1024 + u1];
            L1_KLOOP(0, 1024);
            L1_ENTRY(512, 1536, rev);
            #pragma unroll
            for (int r = 0; r < 16; ++r) {
                iga[r] = ag_in(sigf(P0[r] + bgi) * tanhfast(P1[r] + bgg));
            }
        }
        // ===== L1 pass 1: gates f,o -> cell update + h =====
        {
            f32x16 P0, P1;
            #pragma unroll
            for (int r = 0; r < 16; ++r) { P0[r] = 0.0f; P1[r] = 0.0f; }
            float bgf = b1[512 + u1], bgo = b1[1536 + u1];
            L1_KLOOP(512, 1536);
            bar_lds();   // B
            #pragma unroll
            for (int r = 0; r < 16; ++r) {
                float F = sigf(P0[r] + bgf);
                float O = sigf(P1[r] + bgo);
                float c = F * ag_out(c1a[r]) + ag_out(iga[r]);
                c1a[r] = ag_in(c);
                float h = O * tanhfast(c);
                int row = (r & 3) + 8 * (r >> 2) + 4 * kh;
                h1b[row * 520 + u1] = f2h(h);
            }
        }
        bar_lds();   // C

        unsigned short xv16a = 0, xv16b = 0;
        float xv0 = 0.0f, xv1 = 0.0f;
        if (t + 1 < NTIME) {
            int b = tid >> 6, f = tid & 63;
            if (xtmode) {
                const unsigned short* p = xt2 + (((size_t)wg * 30 + (t + 1)) * 32 + b) * 64 + f;
                xv16a = p[0];
                xv16b = p[16 * 64];
            } else {
                int idx = (samp0 + b) * 1740 + f * 30 + (t + 1);
                xv0 = (f < 58) ? x1[idx] : 0.0f;
                xv1 = (f < 58) ? x2[idx] : 0.0f;
            }
        }

        L2_ENTRY();

        if (t + 1 < NTIME) {
            unsigned short* xb2 = xb + ((t + 1) & 1) * 2304;
            int b = tid >> 6, f = tid & 63;
            if (xtmode) {
                xb2[b * 72 + f] = xv16a;
                xb2[(16 + b) * 72 + f] = xv16b;
            } else {
                xb2[b * 72 + f] = f2h(xv0);
                xb2[(16 + b) * 72 + f] = f2h(xv1);
            }
        }

        // ===== L2 =====
        {
            f32x4 A0 = {0.0f, 0.0f, 0.0f, 0.0f};
            f32x4 A1 = {0.0f, 0.0f, 0.0f, 0.0f};
            f32x4 A2 = {0.0f, 0.0f, 0.0f, 0.0f};
            f32x4 A3 = {0.0f, 0.0f, 0.0f, 0.0f};
            float bg0 = b2[u2], bg1 = b2[128 + u2], bg2 = b2[256 + u2], bg3 = b2[384 + u2];
            #pragma unroll 1
            for (int ss = 0; ss < 20; ss += 2) {
                L2_SUB(qa0, qa1, qa2, qa3, 0);
                L2_SUB(qb0, qb1, qb2, qb3, 1);
            }
            if (wv < 8) { L3_ENTRY_A(); }
            #pragma unroll
            for (int r = 0; r < 4; ++r) {
                float I = sigf(A0[r] + bg0);
                float F = sigf(A1[r] + bg1);
                float G = tanhfast(A2[r] + bg2);
                float O = sigf(A3[r] + bg3);
                float c = F * ag_out(c2a[r]) + I * G;
                c2a[r] = ag_in(c);
                float h = O * tanhfast(c);
                int row = mt2 * 16 + quad * 4 + r;
                h2b[nxt * 4352 + row * 136 + u2] = f2h(h);
            }
        }
        bar_lds();   // D

        // ===== L3 =====
        if (wv < 8) {
            f32x4 A0 = {0.0f, 0.0f, 0.0f, 0.0f};
            f32x4 A1 = {0.0f, 0.0f, 0.0f, 0.0f};
            f32x4 A2 = {0.0f, 0.0f, 0.0f, 0.0f};
            f32x4 A3 = {0.0f, 0.0f, 0.0f, 0.0f};
            float bg0 = b3[u3], bg1 = b3[64 + u3], bg2 = b3[128 + u3], bg3 = b3[192 + u3];
            L3_ENTRY_B();
            #pragma unroll 1
            for (int ss = 0; ss < 6; ss += 2) {
                L3_SUB(ra0, ra1, ra2, ra3, 0);
                L3_SUB(rb0, rb1, rb2, rb3, 1);
            }
            #pragma unroll
            for (int r = 0; r < 4; ++r) {
                float I = sigf(A0[r] + bg0);
                float F = sigf(A1[r] + bg1);
                float G = tanhfast(A2[r] + bg2);
                float O = sigf(A3[r] + bg3);
                float c = F * ag_out(c3a[r]) + I * G;
                c3a[r] = ag_in(c);
                float h = O * tanhfast(c);
                int row = mt3 * 16 + quad * 4 + r;
                h3b[nxt * 2304 + row * 72 + u3] = f2h(h);
            }
        }

        if (t + 1 < NTIME) {
            L1_ENTRY(0, 1024, !rev);
        }
        bar_lds();   // E

        // d = |relu(h3_x1) - relu(h3_x2)| -> global, fp16
        {
            int b = tid >> 6, u = tid & 63;
            float ha = h2f(h3b[nxt * 2304 + b * 72 + u]);
            float hb = h2f(h3b[nxt * 2304 + (16 + b) * 72 + u]);
            dbuf[(size_t)(samp0 + b) * 1920 + t * 64 + u] =
                f2h(fabsf(fmaxf(ha, 0.0f) - fmaxf(hb, 0.0f)));
        }
        cur = nxt;
    }
}

// ---- FC head v3: MFMA fc1/fc2 on fp16, vector fc3/fc4.
// 256 WGs x 16 samples x 1024 thr. D-tile staged once in LDS (padded stride
// 1928 shorts: byte-stride 3856 -> bank offset 4 -> 2-way only, free).
// fc1: wave w owns cgs {w, w+16, w+32, w+48<60}; 60 ksteps; B-frags from
// w1p (3.7 MB, per-XCD L2 resident). fc2: cgs {w, w+16<30}; 30 ksteps.
// Fragment conventions identical to the validated L2/L3 path.
__global__ __launch_bounds__(1024, 4) void head_v3(
    const unsigned short* __restrict__ dg,
    const unsigned short* __restrict__ w1p, const float* __restrict__ bf1,
    const unsigned short* __restrict__ w2p, const float* __restrict__ bf2,
    const float* __restrict__ Wf3, const float* __restrict__ bf3,
    const float* __restrict__ Wf4, const float* __restrict__ bf4,
    float* __restrict__ out)
{
    extern __shared__ unsigned short hsm[];
    unsigned short* dsh = hsm;                    // [16][1928] fp16 D tile
    unsigned short* a1h = hsm + 16 * 1928;        // [16][968] fp16 relu(fc1)
    float* a2f = (float*)(hsm + 16 * 1928 + 16 * 968);   // [16][488] f32 relu(fc2)
    float* a3  = a2f + 16 * 488;                  // [16][16]

    const int tid  = threadIdx.x;
    const int wv   = tid >> 6;
    const int lane = tid & 63;
    const int n2   = lane & 15;
    const int quad = lane >> 4;
    const int samp0 = blockIdx.x * 16;

    // stage D tile: [16][1920] fp16, coalesced (30720 = 30*1024 exact)
    for (int e = tid; e < 30720; e += 1024) {
        int row = e / 1920, col = e - row * 1920;
        dsh[row * 1928 + col] = dg[(size_t)(samp0 + row) * 1920 + col];
    }
    __syncthreads();

    // ===== fc1: [16x1920] x [1920x960] via MFMA16, K=60 ksteps =====
    {
        const int cgA = wv, cgB = wv + 16, cgC = wv + 32, cgD = wv + 48;
        const bool hasD = (cgD < 60);
        f32x4 A0 = {0.0f, 0.0f, 0.0f, 0.0f};
        f32x4 A1 = {0.0f, 0.0f, 0.0f, 0.0f};
        f32x4 A2 = {0.0f, 0.0f, 0.0f, 0.0f};
        f32x4 A3 = {0.0f, 0.0f, 0.0f, 0.0f};
        #pragma unroll 1
        for (int s = 0; s < 60; ++s) {
            half8 af = *(const half8*)(dsh + n2 * 1928 + s * 32 + quad * 8);
            const unsigned short* bs = w1p + (size_t)s * 60 * 512 + lane * 8;
            half8 b0 = *(const half8*)(bs + cgA * 512);
            half8 b1 = *(const half8*)(bs + cgB * 512);
            half8 b2 = *(const half8*)(bs + cgC * 512);
            MFMA16(A0, af, b0);
            MFMA16(A1, af, b1);
            MFMA16(A2, af, b2);
            if (hasD) {
                half8 b3 = *(const half8*)(bs + cgD * 512);
                MFMA16(A3, af, b3);
            }
        }
        float biA = bf1[cgA * 16 + n2];
        float biB = bf1[cgB * 16 + n2];
        float biC = bf1[cgC * 16 + n2];
        float biD = hasD ? bf1[cgD * 16 + n2] : 0.0f;
        #pragma unroll
        for (int r = 0; r < 4; ++r) {
            int row = quad * 4 + r;
            a1h[row * 968 + cgA * 16 + n2] = f2h(fmaxf(A0[r] + biA, 0.0f));
            a1h[row * 968 + cgB * 16 + n2] = f2h(fmaxf(A1[r] + biB, 0.0f));
            a1h[row * 968 + cgC * 16 + n2] = f2h(fmaxf(A2[r] + biC, 0.0f));
            if (hasD) a1h[row * 968 + cgD * 16 + n2] = f2h(fmaxf(A3[r] + biD, 0.0f));
        }
    }
    __syncthreads();

    // ===== fc2: [16x960] x [960x480] via MFMA16, K=30 ksteps =====
    {
        const int cgA = wv, cgB = wv + 16;
        const bool hasB = (cgB < 30) && (cgA < 30);
        const bool hasA = (cgA < 30);
        f32x4 A0 = {0.0f, 0.0f, 0.0f, 0.0f};
        f32x4 A1 = {0.0f, 0.0f, 0.0f, 0.0f};
        if (hasA) {
            #pragma unroll 1
            for (int s = 0; s < 30; ++s) {
                half8 af = *(const half8*)(a1h + n2 * 968 + s * 32 + quad * 8);
                const unsigned short* bs = w2p + (size_t)s * 30 * 512 + lane * 8;
                half8 b0 = *(const half8*)(bs + cgA * 512);
                MFMA16(A0, af, b0);
                if (hasB) {
                    half8 b1 = *(const half8*)(bs + cgB * 512);
                    MFMA16(A1, af, b1);
                }
            }
            float biA = bf2[cgA * 16 + n2];
            float biB = hasB ? bf2[cgB * 16 + n2] : 0.0f;
            #pragma unroll
            for (int r = 0; r < 4; ++r) {
                int row = quad * 4 + r;
                a2f[row * 488 + cgA * 16 + n2] = fmaxf(A0[r] + biA, 0.0f);
                if (hasB) a2f[row * 488 + cgB * 16 + n2] = fmaxf(A1[r] + biB, 0.0f);
            }
        }
    }
    __syncthreads();

    // ===== fc3: [16x480] x [480x16], vector =====
    if (tid < 256) {
        int o = tid & 15, r = tid >> 4;
        float acc = bf3[o];
        const float4* wr = (const float4*)(Wf3 + (size_t)o * 480);
        const float4* av = (const float4*)(a2f + r * 488);
        #pragma unroll 4
        for (int kc = 0; kc < 120; ++kc) {
            float4 a4 = av[kc];
            float4 w4 = wr[kc];
            acc += a4.x * w4.x + a4.y * w4.y + a4.z * w4.z + a4.w * w4.w;
        }
        a3[r * 16 + o] = fmaxf(acc, 0.0f);
    }
    __syncthreads();

    // ===== fc4 =====
    if (tid < 16) {
        float acc = bf4[0];
        #pragma unroll
        for (int k = 0; k < 16; ++k) acc += a3[tid * 16 + k] * Wf4[k];
        out[samp0 + tid] = acc;
    }
}

extern "C" void kernel_launch(void* const* d_in, const int* in_sizes, int n_in,
                              void* d_out, int out_size, void* d_ws, size_t ws_size,
                              hipStream_t stream) {
    const float* x1   = (const float*)d_in[0];
    const float* x2   = (const float*)d_in[1];
    const float* Wih1 = (const float*)d_in[2];
    const float* Whh1 = (const float*)d_in[3];
    const float* b1   = (const float*)d_in[4];
    const float* Wih2 = (const float*)d_in[5];
    const float* Whh2 = (const float*)d_in[6];
    const float* b2   = (const float*)d_in[7];
    const float* Wih3 = (const float*)d_in[8];
    const float* Whh3 = (const float*)d_in[9];
    const float* b3   = (const float*)d_in[10];
    const float* Wf1  = (const float*)d_in[11];
    const float* bf1  = (const float*)d_in[12];
    const float* Wf2  = (const float*)d_in[13];
    const float* bf2  = (const float*)d_in[14];
    const float* Wf3  = (const float*)d_in[15];
    const float* bf3  = (const float*)d_in[16];
    const float* Wf4  = (const float*)d_in[17];
    const float* bf4  = (const float*)d_in[18];

    float* wsf = (float*)d_ws;
    // layout (f32 units):
    unsigned short* dbuf = (unsigned short*)wsf;               // 7,864,320 us  -> +3,932,160
    unsigned short* l1w  = (unsigned short*)(wsf + 3932160);   // 1,179,648 us  -> +589,824
    unsigned short* l2w  = (unsigned short*)(wsf + 4521984);   //   327,680 us  -> +163,840
    unsigned short* l3w  = (unsigned short*)(wsf + 4685824);   //    49,152 us  -> +24,576
    unsigned short* w1p  = (unsigned short*)(wsf + 4710400);   // 1,843,200 us  -> +921,600
    unsigned short* w2p  = (unsigned short*)(wsf + 5632000);   //   460,800 us  -> +230,400
    unsigned short* xt2  = (unsigned short*)(wsf + 5862400);   // 15,728,640 us -> +7,864,320
    float* out = (float*)d_out;

    const size_t need_bytes = (size_t)(5862400 + 7864320) * 4u;
    const int xtmode = (ws_size >= need_bytes) ? 1 : 0;

    prep_w32s<<<(36 * 32768) / 256, 256, 0, stream>>>(Wih1, Whh1, l1w);
    prep_w16s<<<(20 * 8 * 2048) / 256, 256, 0, stream>>>(Wih2, Whh2, l2w, 128, 512, 512, 128, 8, 20);
    prep_w16s<<<(6 * 4 * 2048) / 256, 256, 0, stream>>>(Wih3, Whh3, l3w, 64, 128, 128, 64, 4, 6);
    prep_hw1<<<(60 * 60 * 512) / 256, 256, 0, stream>>>(Wf1, w1p);
    prep_hw2<<<(30 * 30 * 512) / 256, 256, 0, stream>>>(Wf2, w2p);
    if (xtmode) {
        prep_xt2<<<8192, 256, 0, stream>>>(x1, x2, xt2);
    }

    (void)hipFuncSetAttribute((const void*)lstm3_v13,
                              hipFuncAttributeMaxDynamicSharedMemorySize, 69120);
    lstm3_v13<<<256, 1024, 69120, stream>>>(x1, x2, xt2, xtmode,
                                            l1w, l2w, l3w, b1, b2, b3, dbuf);

    // head LDS: 16*1928 + 16*968 shorts = 92,672 B; + 16*488 f32 = 31,232 B;
    // + 256 f32 = 1,024 B  ->  124,928 B
    (void)hipFuncSetAttribute((const void*)head_v3,
                              hipFuncAttributeMaxDynamicSharedMemorySize, 124928);
    head_v3<<<256, 1024, 124928, stream>>>(dbuf, w1p, bf1, w2p, bf2,
                                           Wf3, bf3, Wf4, bf4, out);
}